// Round 11
// baseline (153.448 us; speedup 1.0000x reference)
//
#include <hip/hip_runtime.h>
#include <hip/hip_bf16.h>

#define NN 10000
#define TT 8
#define LL 3
#define NGRP 625     // 10000 / 16 exactly

// out layout: ys [N][T][64] = 5,120,000 f32 | h [N][64] = 640,000 | c [N][64]
#define OUT_ELEMS 6400000
#define H_OFF 5120000
#define C_OFF 5760000

typedef __bf16 bf16;
typedef __attribute__((ext_vector_type(8))) __bf16 bf16x8;
typedef __attribute__((ext_vector_type(4))) float f32x4;
typedef __attribute__((ext_vector_type(16))) float f32x16;

// v_rcp_f32 (1 instr) instead of IEEE divide — bf16-grade accuracy (verified r4).
__device__ __forceinline__ float sigf(float x) {
    return __builtin_amdgcn_rcpf(1.0f + __expf(-x));
}
__device__ __forceinline__ float tanhf_(float x) {
    return fmaf(2.0f, __builtin_amdgcn_rcpf(1.0f + __expf(-2.0f * x)), -1.0f);
}

// ---------------------------------------------------------------------------
// prep: repack LSTM weights into bf16 B-fragment order + combine biases
// + cast X (f32, 5.12 MB) to Xh (bf16, 2.56 MB; fits one XCD's 4 MB L2).
// wts layout (bf16): [l][mat][kh][nt][n16][k32]
// ---------------------------------------------------------------------------
__global__ void prep_kernel(const float* __restrict__ X,
                            const float* __restrict__ W_ih, const float* __restrict__ W_hh,
                            const float* __restrict__ b_ih, const float* __restrict__ b_hh,
                            bf16* __restrict__ wts, float* __restrict__ bias,
                            bf16* __restrict__ Xh) {
    int id = blockIdx.x * 256 + threadIdx.x;
    if (id < LL * 2 * 256 * 64) {
        int col = id & 63;
        int row = (id >> 6) & 255;
        int mat = (id >> 14) & 1;
        int l = id >> 15;
        const float* src = mat ? W_hh : W_ih;
        float w = src[(l * 256 + row) * 64 + col];
        int kh = col >> 5, nt = row >> 4, nn = row & 15, kk = col & 31;
        wts[((((l * 2 + mat) * 2 + kh) * 16 + nt) * 16 + nn) * 32 + kk] = (bf16)w;
    } else if (id < LL * 2 * 256 * 64 + LL * 256) {
        int id2 = id - LL * 2 * 256 * 64;
        bias[id2] = b_ih[id2] + b_hh[id2];
    } else if (Xh != nullptr) {
        int id3 = id - (LL * 2 * 256 * 64 + LL * 256);
        if (id3 < NN * TT) {        // one 16-channel row per thread
            const float* xr = X + (long)id3 * 16;
            f32x4 a = *(const f32x4*)xr,       b = *(const f32x4*)(xr + 4);
            f32x4 c = *(const f32x4*)(xr + 8), d = *(const f32x4*)(xr + 12);
            bf16x8 lo, hi;
#pragma unroll
            for (int j = 0; j < 4; ++j) {
                lo[j] = (bf16)a[j]; lo[4 + j] = (bf16)b[j];
                hi[j] = (bf16)c[j]; hi[4 + j] = (bf16)d[j];
            }
            bf16* xo = Xh + (long)id3 * 16;
            *(bf16x8*)xo = lo;
            *(bf16x8*)(xo + 8) = hi;
        }
    }
}

// ---------------------------------------------------------------------------
// mega_kernel v5 (r4/r6 proven-best base + 4-buffer full gather hoist):
// ONE block = 16 nodes x ALL 3 levels (768 threads, 12 waves; quad lq =
// level lq). Cross-level max in LDS -> no slabs, no reduce kernel; out
// written once, coalesced f32x4, temporally clustered (r3 lesson).
// v5 change: each conv chunk gets its OWN register buffer (gA..gD, 64
// VGPRs) so all 16 Xh gathers issue back-to-back right after the As-index
// loads — ONE latency exposure instead of ~3 (the 2-deep pipeline made
// chunk-2/3 gathers wait on proc(0)/proc(1) consuming their shared regs).
// Session evidence (r5/r9/r10): scheduling-level changes (dbuf, lgkm
// barriers, prefetch, store placement) are all neutral; 2-block residency
// of 768-thread blocks is impossible (85-reg cap -> spill, r5); this
// structure's per-block wall ~30 us is the co-residency-limited floor.
// Conv: bf16 Xh gathers (16 B load IS the A-frag), ego-split
// max_k((g-s)W) = max_k(gW) - sW with sW in registers via one shfl_xor(32)
// (from the verified 32x32 D-layout row=(g&3)+8*(g>>2)+4*hh).
// ---------------------------------------------------------------------------
__global__ __launch_bounds__(768, 3) void mega_kernel(
    const bf16* __restrict__ Xh, const int* __restrict__ As,
    const float* __restrict__ conv_w, const float* __restrict__ conv_b,
    const bf16* __restrict__ wts, const float* __restrict__ bias,
    float* __restrict__ out) {
    __shared__ __align__(16) bf16 featL[LL][TT][16][72];   // 55,296 B
    __shared__ __align__(16) bf16 hlds[LL][2][16][72];     // 13,824 B
    __shared__ __align__(16) float yst[LL][2][16][64];     // 24,576 B (ping-pong)

    const int tid = threadIdx.x;
    const int node0 = blockIdx.x * 16;
    const int lq = tid >> 8;            // level 0..2
    const int tl = tid & 255;           // thread-in-quad
    const int lane = tid & 63;
    const int wq = tl >> 6;             // wave-in-quad 0..3
    const int c16 = lane & 15;
    const int q = lane >> 4;
    const int m = lane & 31;            // conv: A row index
    const int hh = lane >> 5;           // conv: k-half
    const int ch0 = hh * 8;
    const int nsub = m >> 4;
    const int kn = m & 15;

    // ================= conv weights -> B fragments =================
    bf16x8 B0, B1;
    {
        const float* w0 = conv_w + ((lq * 64 + m) * 16 + ch0);
        f32x4 a = *(const f32x4*)w0, b = *(const f32x4*)(w0 + 4);
        const float* w1 = conv_w + ((lq * 64 + 32 + m) * 16 + ch0);
        f32x4 c = *(const f32x4*)w1, d = *(const f32x4*)(w1 + 4);
#pragma unroll
        for (int j = 0; j < 4; ++j) {
            B0[j] = (bf16)a[j]; B0[4 + j] = (bf16)b[j];
            B1[j] = (bf16)c[j]; B1[4 + j] = (bf16)d[j];
        }
    }
    const float cb0 = conv_b[lq * 64 + m];
    const float cb1 = conv_b[lq * 64 + 32 + m];

    // ========== 1) hoist ALL 16 As-index loads (one latency) ==========
    int aidx[4][4];
#pragma unroll
    for (int c = 0; c < 4; ++c) {
        const int t0 = (c >> 1) * 4;
        const int gn = node0 + 2 * (2 * wq + (c & 1)) + nsub;
#pragma unroll
        for (int j = 0; j < 4; ++j)
            aidx[c][j] = As[((long)(lq * 8 + t0 + j) * NN + gn) * 16 + kn];
    }

    // ========== 2) ego projection sW in registers (overlaps As latency) ==========
    f32x16 E0, E1;
    {
        bf16x8 ae = *(const bf16x8*)(Xh + ((long)(node0 * 8 + 32 * wq + m)) * 16 + ch0);
#pragma unroll
        for (int k = 0; k < 16; ++k) { E0[k] = 0.0f; E1[k] = 0.0f; }
        E0 = __builtin_amdgcn_mfma_f32_32x32x16_bf16(ae, B0, E0, 0, 0, 0);
        E1 = __builtin_amdgcn_mfma_f32_32x32x16_bf16(ae, B1, E1, 0, 0, 0);
    }

    // ========== 3) gathers: 4 private buffers, ALL 16 issue up-front ==========
    bf16x8 gA[4], gB[4], gC[4], gD[4];
    auto gload = [&](int c, bf16x8* dst) {
        const int t0 = (c >> 1) * 4;
#pragma unroll
        for (int j = 0; j < 4; ++j)
            dst[j] = *(const bf16x8*)(Xh + ((long)aidx[c][j] * 8 + t0 + j) * 16 + ch0);
    };
    auto proc = [&](int c, const bf16x8* g) {
        const int t0 = (c >> 1) * 4;
        const int pc = 2 * wq + (c & 1);
#pragma unroll
        for (int j = 0; j < 4; ++j) {
            f32x16 D0, D1;
#pragma unroll
            for (int k = 0; k < 16; ++k) { D0[k] = 0.0f; D1[k] = 0.0f; }
            D0 = __builtin_amdgcn_mfma_f32_32x32x16_bf16(g[j], B0, D0, 0, 0, 0);
            D1 = __builtin_amdgcn_mfma_f32_32x32x16_bf16(g[j], B1, D1, 0, 0, 0);

            float v00 = D0[0], v01 = D1[0], v10 = D0[8], v11 = D1[8];
#pragma unroll
            for (int k = 1; k < 8; ++k) {
                v00 = fmaxf(v00, D0[k]);     v01 = fmaxf(v01, D1[k]);
                v10 = fmaxf(v10, D0[8 + k]); v11 = fmaxf(v11, D1[8 + k]);
            }
            v00 = fmaxf(v00, __shfl_xor(v00, 32));
            v01 = fmaxf(v01, __shfl_xor(v01, 32));
            v10 = fmaxf(v10, __shfl_xor(v10, 32));
            v11 = fmaxf(v11, __shfl_xor(v11, 32));

            const float sA = hh ? v10 : v00;   // cols [0,32)
            const float sB = hh ? v11 : v01;   // cols [32,64)

            // sW from registers: bands (compile-time const indices)
            const float a0 = E0[j + 8 * (c & 1)];       // hh_c = 0 band
            const float a1 = E0[j + 8 * (c & 1) + 4];   // hh_c = 1 band
            const float b0 = E1[j + 8 * (c & 1)];
            const float b1 = E1[j + 8 * (c & 1) + 4];
            const float sendA = hh ? a0 : a1;           // what my partner needs
            const float sendB = hh ? b0 : b1;
            const float rcvA = __shfl_xor(sendA, 32);
            const float rcvB = __shfl_xor(sendB, 32);
            const bool loc = (hh == (c >> 1));          // source half = c>>1
            const float swA = loc ? (hh ? a1 : a0) : rcvA;
            const float swB = loc ? (hh ? b1 : b0) : rcvB;

            featL[lq][t0 + j][2 * pc + hh][m]      = (bf16)(sA + cb0 - swA);
            featL[lq][t0 + j][2 * pc + hh][32 + m] = (bf16)(sB + cb1 - swB);
        }
    };
    gload(0, gA); gload(1, gB); gload(2, gC); gload(3, gD);
    proc(0, gA);  proc(1, gB);  proc(2, gC);  proc(3, gD);

    // ================= LSTM weights (registers/AGPRs) =================
    const bf16* wb = wts + lq * 32768;
    const int fo = c16 * 32 + q * 8;
    bf16x8 Bx0[4], Bx1[4], Bh0[4], Bh1[4];
    float brg[4];
#pragma unroll
    for (int g = 0; g < 4; ++g) {
        const int nt = 4 * g + wq;
        Bx0[g] = *(const bf16x8*)(wb + (0 * 16 + nt) * 512 + fo);
        Bx1[g] = *(const bf16x8*)(wb + (1 * 16 + nt) * 512 + fo);
        Bh0[g] = *(const bf16x8*)(wb + (2 * 16 + nt) * 512 + fo);
        Bh1[g] = *(const bf16x8*)(wb + (3 * 16 + nt) * 512 + fo);
        brg[g] = bias[lq * 256 + nt * 16 + c16];
    }
    float c_r[4];
#pragma unroll
    for (int r = 0; r < 4; ++r) c_r[r] = 0.0f;

    const int col = wq * 16 + c16;
    const int sn = tl >> 4;             // store mapping (lq==0 quad)
    const int sc = (tl & 15) * 4;

    // ================= 8 recurrent steps =================
#pragma unroll
    for (int t = 0; t < TT; ++t) {
        __syncthreads();  // t=0: featL ready; t>0: h(t-1)/yst(t-1) visible

        if (t > 0 && tid < 256) {   // cross-level max of ys(t-1), coalesced store
            f32x4 y0 = *(const f32x4*)&yst[0][(t - 1) & 1][sn][sc];
            f32x4 y1 = *(const f32x4*)&yst[1][(t - 1) & 1][sn][sc];
            f32x4 y2 = *(const f32x4*)&yst[2][(t - 1) & 1][sn][sc];
            f32x4 dmx;
#pragma unroll
            for (int k = 0; k < 4; ++k) dmx[k] = fmaxf(fmaxf(y0[k], y1[k]), y2[k]);
            *(f32x4*)&out[((long)(node0 + sn) * 8 + (t - 1)) * 64 + sc] = dmx;
        }

        bf16x8 ax0 = *(const bf16x8*)&featL[lq][t][c16][q * 8];
        bf16x8 ax1 = *(const bf16x8*)&featL[lq][t][c16][32 + q * 8];
        bf16x8 ah0, ah1;
        if (t > 0) {
            ah0 = *(const bf16x8*)&hlds[lq][(t + 1) & 1][c16][q * 8];
            ah1 = *(const bf16x8*)&hlds[lq][(t + 1) & 1][c16][32 + q * 8];
        }

        f32x4 acc[4];
#pragma unroll
        for (int g = 0; g < 4; ++g) {
            float b = brg[g];
            acc[g] = (f32x4){b, b, b, b};
            acc[g] = __builtin_amdgcn_mfma_f32_16x16x32_bf16(ax0, Bx0[g], acc[g], 0, 0, 0);
            acc[g] = __builtin_amdgcn_mfma_f32_16x16x32_bf16(ax1, Bx1[g], acc[g], 0, 0, 0);
            if (t > 0) {
                acc[g] = __builtin_amdgcn_mfma_f32_16x16x32_bf16(ah0, Bh0[g], acc[g], 0, 0, 0);
                acc[g] = __builtin_amdgcn_mfma_f32_16x16x32_bf16(ah1, Bh1[g], acc[g], 0, 0, 0);
            }
        }

        // cell: lane holds nodes q*4+r, hidden col wq*16+c16
#pragma unroll
        for (int r = 0; r < 4; ++r) {
            float iv = acc[0][r], fv = acc[1][r], gg = acc[2][r], ov = acc[3][r];
            float c = sigf(fv) * c_r[r] + sigf(iv) * tanhf_(gg);
            c_r[r] = c;
            float h = sigf(ov) * tanhf_(c);
            hlds[lq][t & 1][q * 4 + r][col] = (bf16)h;
            yst[lq][t & 1][q * 4 + r][col] = h;
        }
    }

    // ================= tail: ys(7)=h_final, then c_final =================
    __syncthreads();            // step-7 writes + y(6) store reads complete
#pragma unroll
    for (int r = 0; r < 4; ++r) // stage c in slot 0 (y(6) already consumed)
        yst[lq][0][q * 4 + r][col] = c_r[r];
    if (tid < 256) {
        f32x4 y0 = *(const f32x4*)&yst[0][1][sn][sc];
        f32x4 y1 = *(const f32x4*)&yst[1][1][sn][sc];
        f32x4 y2 = *(const f32x4*)&yst[2][1][sn][sc];
        f32x4 dmx;
#pragma unroll
        for (int k = 0; k < 4; ++k) dmx[k] = fmaxf(fmaxf(y0[k], y1[k]), y2[k]);
        *(f32x4*)&out[((long)(node0 + sn) * 8 + 7) * 64 + sc] = dmx;
        *(f32x4*)&out[H_OFF + (long)(node0 + sn) * 64 + sc] = dmx;
    }
    __syncthreads();
    if (tid < 256) {
        f32x4 c0 = *(const f32x4*)&yst[0][0][sn][sc];
        f32x4 c1 = *(const f32x4*)&yst[1][0][sn][sc];
        f32x4 c2 = *(const f32x4*)&yst[2][0][sn][sc];
        f32x4 dmx;
#pragma unroll
        for (int k = 0; k < 4; ++k) dmx[k] = fmaxf(fmaxf(c0[k], c1[k]), c2[k]);
        *(f32x4*)&out[C_OFF + (long)(node0 + sn) * 64 + sc] = dmx;
    }
}

// ---------------------------------------------------------------------------
// Path B (fallback if ws too small): r6 structure — in-block level loop,
// direct out writes, f32 X. Proven correct.
// ---------------------------------------------------------------------------
__device__ __forceinline__ void level_body(
    int l, int node0, int tid,
    const float* __restrict__ X, const int* __restrict__ As,
    const float* __restrict__ conv_w, const float* __restrict__ conv_b,
    const bf16* __restrict__ wts, const float* __restrict__ bias,
    bf16 (*featL)[16][72], bf16 (*hlds)[16][72],
    float ymax[TT][4], float hfin[4], float cfin[4], bool accum) {
    const int lane = tid & 63;
    const int wv = tid >> 6;
    const int c16 = lane & 15;
    const int q = lane >> 4;
    const int m = lane & 31;
    const int hh = lane >> 5;
    const int ch0 = hh * 8;
    const int nsub = m >> 4;
    const int kn = m & 15;

    bf16x8 B0, B1;
    {
        const float* w0 = conv_w + ((l * 64 + m) * 16 + ch0);
        f32x4 a = *(const f32x4*)w0, b = *(const f32x4*)(w0 + 4);
        const float* w1 = conv_w + ((l * 64 + 32 + m) * 16 + ch0);
        f32x4 c = *(const f32x4*)w1, d = *(const f32x4*)(w1 + 4);
#pragma unroll
        for (int j = 0; j < 4; ++j) {
            B0[j] = (bf16)a[j]; B0[4 + j] = (bf16)b[j];
            B1[j] = (bf16)c[j]; B1[4 + j] = (bf16)d[j];
        }
    }
    const float cb0 = conv_b[l * 64 + m];
    const float cb1 = conv_b[l * 64 + 32 + m];

#pragma unroll 1
    for (int c = 0; c < 4; ++c) {
        const int pc = 2 * wv + (c & 1);
        const int t0 = (c >> 1) * 4;
        const int gn = node0 + 2 * pc + nsub;

        int aidx[4];
#pragma unroll
        for (int j = 0; j < 4; ++j)
            aidx[j] = As[((long)(l * 8 + t0 + j) * NN + gn) * 16 + kn];
        f32x4 sv[4][2], gv[4][2];
#pragma unroll
        for (int j = 0; j < 4; ++j) {
            const float* sp = X + ((gn * 8 + t0 + j) * 16 + ch0);
            sv[j][0] = *(const f32x4*)sp;
            sv[j][1] = *(const f32x4*)(sp + 4);
        }
#pragma unroll
        for (int j = 0; j < 4; ++j) {
            const float* gp = X + (((long)aidx[j] * 8 + t0 + j) * 16 + ch0);
            gv[j][0] = *(const f32x4*)gp;
            gv[j][1] = *(const f32x4*)(gp + 4);
        }

#pragma unroll
        for (int j = 0; j < 4; ++j) {
            bf16x8 af;
#pragma unroll
            for (int k = 0; k < 4; ++k) {
                af[k]     = (bf16)(gv[j][0][k] - sv[j][0][k]);
                af[4 + k] = (bf16)(gv[j][1][k] - sv[j][1][k]);
            }
            f32x16 D0, D1;
#pragma unroll
            for (int k = 0; k < 16; ++k) { D0[k] = 0.0f; D1[k] = 0.0f; }
            D0 = __builtin_amdgcn_mfma_f32_32x32x16_bf16(af, B0, D0, 0, 0, 0);
            D1 = __builtin_amdgcn_mfma_f32_32x32x16_bf16(af, B1, D1, 0, 0, 0);

            float v00 = D0[0], v01 = D1[0], v10 = D0[8], v11 = D1[8];
#pragma unroll
            for (int k = 1; k < 8; ++k) {
                v00 = fmaxf(v00, D0[k]);     v01 = fmaxf(v01, D1[k]);
                v10 = fmaxf(v10, D0[8 + k]); v11 = fmaxf(v11, D1[8 + k]);
            }
            v00 = fmaxf(v00, __shfl_xor(v00, 32));
            v01 = fmaxf(v01, __shfl_xor(v01, 32));
            v10 = fmaxf(v10, __shfl_xor(v10, 32));
            v11 = fmaxf(v11, __shfl_xor(v11, 32));

            const float sA = hh ? v10 : v00;
            const float sB = hh ? v11 : v01;
            featL[t0 + j][2 * pc + hh][m]      = (bf16)(sA + cb0);
            featL[t0 + j][2 * pc + hh][32 + m] = (bf16)(sB + cb1);
        }
    }

    const bf16* wb = wts + l * 32768;
    const int fo = c16 * 32 + q * 8;
    bf16x8 Bx0[4], Bx1[4], Bh0[4], Bh1[4];
    float brg[4];
#pragma unroll
    for (int g = 0; g < 4; ++g) {
        const int nt = 4 * g + wv;
        Bx0[g] = *(const bf16x8*)(wb + (0 * 16 + nt) * 512 + fo);
        Bx1[g] = *(const bf16x8*)(wb + (1 * 16 + nt) * 512 + fo);
        Bh0[g] = *(const bf16x8*)(wb + (2 * 16 + nt) * 512 + fo);
        Bh1[g] = *(const bf16x8*)(wb + (3 * 16 + nt) * 512 + fo);
        brg[g] = bias[l * 256 + nt * 16 + c16];
    }
    float c_r[4];
#pragma unroll
    for (int r = 0; r < 4; ++r) c_r[r] = 0.0f;

#pragma unroll
    for (int t = 0; t < TT; ++t) {
        __syncthreads();

        bf16x8 ax0 = *(const bf16x8*)&featL[t][c16][q * 8];
        bf16x8 ax1 = *(const bf16x8*)&featL[t][c16][32 + q * 8];
        bf16x8 ah0, ah1;
        if (t > 0) {
            ah0 = *(const bf16x8*)&hlds[(t + 1) & 1][c16][q * 8];
            ah1 = *(const bf16x8*)&hlds[(t + 1) & 1][c16][32 + q * 8];
        }

        f32x4 acc[4];
#pragma unroll
        for (int g = 0; g < 4; ++g) {
            float b = brg[g];
            acc[g] = (f32x4){b, b, b, b};
            acc[g] = __builtin_amdgcn_mfma_f32_16x16x32_bf16(ax0, Bx0[g], acc[g], 0, 0, 0);
            acc[g] = __builtin_amdgcn_mfma_f32_16x16x32_bf16(ax1, Bx1[g], acc[g], 0, 0, 0);
            if (t > 0) {
                acc[g] = __builtin_amdgcn_mfma_f32_16x16x32_bf16(ah0, Bh0[g], acc[g], 0, 0, 0);
                acc[g] = __builtin_amdgcn_mfma_f32_16x16x32_bf16(ah1, Bh1[g], acc[g], 0, 0, 0);
            }
        }

#pragma unroll
        for (int r = 0; r < 4; ++r) {
            float iv = acc[0][r], fv = acc[1][r], gg = acc[2][r], ov = acc[3][r];
            float c = sigf(fv) * c_r[r] + sigf(iv) * tanhf_(gg);
            c_r[r] = c;
            float h = sigf(ov) * tanhf_(c);
            hlds[t & 1][q * 4 + r][wv * 16 + c16] = (bf16)h;
            ymax[t][r] = accum ? fmaxf(ymax[t][r], h) : h;
            if (t == TT - 1) {
                hfin[r] = accum ? fmaxf(hfin[r], h) : h;
                cfin[r] = accum ? fmaxf(cfin[r], c) : c;
            }
        }
    }
}

__global__ __launch_bounds__(256, 3) void fused_kernel(
    const float* __restrict__ X, const int* __restrict__ As,
    const float* __restrict__ conv_w, const float* __restrict__ conv_b,
    const bf16* __restrict__ wts, const float* __restrict__ bias,
    float* __restrict__ out) {
    __shared__ __align__(16) bf16 featL[TT][16][72];
    __shared__ __align__(16) bf16 hlds[2][16][72];

    const int tid = threadIdx.x;
    const int node0 = blockIdx.x * 16;

    float ymax[TT][4], hfin[4], cfin[4];
    for (int l = 0; l < LL; ++l) {
        __syncthreads();
        level_body(l, node0, tid, X, As, conv_w, conv_b, wts, bias,
                   featL, hlds, ymax, hfin, cfin, /*accum=*/(l > 0));
    }

    const int lane = tid & 63;
    const int wv = tid >> 6;
    const int c16 = lane & 15;
    const int q = lane >> 4;
    const int col = wv * 16 + c16;
#pragma unroll
    for (int t = 0; t < TT; ++t)
#pragma unroll
        for (int r = 0; r < 4; ++r)
            out[((long)(node0 + q * 4 + r) * 8 + t) * 64 + col] = ymax[t][r];
    float* sh = out + (long)H_OFF;
    float* sc = out + (long)C_OFF;
#pragma unroll
    for (int r = 0; r < 4; ++r) {
        sh[(long)(node0 + q * 4 + r) * 64 + col] = hfin[r];
        sc[(long)(node0 + q * 4 + r) * 64 + col] = cfin[r];
    }
}

extern "C" void kernel_launch(void* const* d_in, const int* in_sizes, int n_in,
                              void* d_out, int out_size, void* d_ws, size_t ws_size,
                              hipStream_t stream) {
    const float* X = (const float*)d_in[0];
    const int* As = (const int*)d_in[1];
    const float* conv_w = (const float*)d_in[4];
    const float* conv_b = (const float*)d_in[5];
    const float* W_ih = (const float*)d_in[6];
    const float* W_hh = (const float*)d_in[7];
    const float* b_ih = (const float*)d_in[8];
    const float* b_hh = (const float*)d_in[9];
    float* out = (float*)d_out;

    char* ws = (char*)d_ws;
    // layout: wts (192 KB) | bias (4 KB slot) | Xh (2.56 MB)
    const size_t xh_bytes = (size_t)NN * TT * 16 * 2;
    const size_t need = 196608 + 4096 + xh_bytes;
    const bool big_ws = ws_size >= need;

    // prep grid: 98304 (wts) + 768 (bias) + 80000 (Xh rows) = 179072 ids
    if (big_ws) {
        bf16* wts = (bf16*)ws;
        float* bias = (float*)(ws + 196608);
        bf16* Xh = (bf16*)(ws + 196608 + 4096);
        hipLaunchKernelGGL(prep_kernel, dim3(700), dim3(256), 0, stream,
                           X, W_ih, W_hh, b_ih, b_hh, wts, bias, Xh);
        hipLaunchKernelGGL(mega_kernel, dim3(NGRP), dim3(768), 0, stream,
                           Xh, As, conv_w, conv_b, wts, bias, out);
    } else {
        bf16* wts = (bf16*)ws;
        float* bias = (float*)(ws + 196608);
        hipLaunchKernelGGL(prep_kernel, dim3(700), dim3(256), 0, stream,
                           X, W_ih, W_hh, b_ih, b_hh, wts, bias, (bf16*)nullptr);
        hipLaunchKernelGGL(fused_kernel, dim3(NGRP), dim3(256), 0, stream,
                           X, As, conv_w, conv_b, wts, bias, out);
    }
}

// Round 12
// 149.794 us; speedup vs baseline: 1.0244x; 1.0244x over previous
//
#include <hip/hip_runtime.h>
#include <hip/hip_bf16.h>

#define NN 10000
#define TT 8
#define LL 3
#define NGRP 625     // 10000 / 16 exactly

// out layout: ys [N][T][64] = 5,120,000 f32 | h [N][64] = 640,000 | c [N][64]
#define OUT_ELEMS 6400000
#define H_OFF 5120000
#define C_OFF 5760000

typedef __bf16 bf16;
typedef __attribute__((ext_vector_type(8))) __bf16 bf16x8;
typedef __attribute__((ext_vector_type(4))) float f32x4;
typedef __attribute__((ext_vector_type(16))) float f32x16;

// v_rcp_f32 (1 instr) instead of IEEE divide — bf16-grade accuracy (verified r4).
__device__ __forceinline__ float sigf(float x) {
    return __builtin_amdgcn_rcpf(1.0f + __expf(-x));
}
__device__ __forceinline__ float tanhf_(float x) {
    return fmaf(2.0f, __builtin_amdgcn_rcpf(1.0f + __expf(-2.0f * x)), -1.0f);
}

// ---------------------------------------------------------------------------
// prep: repack LSTM weights into bf16 B-fragment order + combine biases
// + cast X (f32, 5.12 MB) to Xh (bf16, 2.56 MB; fits one XCD's 4 MB L2).
// wts layout (bf16): [l][mat][kh][nt][n16][k32]
// ---------------------------------------------------------------------------
__global__ void prep_kernel(const float* __restrict__ X,
                            const float* __restrict__ W_ih, const float* __restrict__ W_hh,
                            const float* __restrict__ b_ih, const float* __restrict__ b_hh,
                            bf16* __restrict__ wts, float* __restrict__ bias,
                            bf16* __restrict__ Xh) {
    int id = blockIdx.x * 256 + threadIdx.x;
    if (id < LL * 2 * 256 * 64) {
        int col = id & 63;
        int row = (id >> 6) & 255;
        int mat = (id >> 14) & 1;
        int l = id >> 15;
        const float* src = mat ? W_hh : W_ih;
        float w = src[(l * 256 + row) * 64 + col];
        int kh = col >> 5, nt = row >> 4, nn = row & 15, kk = col & 31;
        wts[((((l * 2 + mat) * 2 + kh) * 16 + nt) * 16 + nn) * 32 + kk] = (bf16)w;
    } else if (id < LL * 2 * 256 * 64 + LL * 256) {
        int id2 = id - LL * 2 * 256 * 64;
        bias[id2] = b_ih[id2] + b_hh[id2];
    } else if (Xh != nullptr) {
        int id3 = id - (LL * 2 * 256 * 64 + LL * 256);
        if (id3 < NN * TT) {        // one 16-channel row per thread
            const float* xr = X + (long)id3 * 16;
            f32x4 a = *(const f32x4*)xr,       b = *(const f32x4*)(xr + 4);
            f32x4 c = *(const f32x4*)(xr + 8), d = *(const f32x4*)(xr + 12);
            bf16x8 lo, hi;
#pragma unroll
            for (int j = 0; j < 4; ++j) {
                lo[j] = (bf16)a[j]; lo[4 + j] = (bf16)b[j];
                hi[j] = (bf16)c[j]; hi[4 + j] = (bf16)d[j];
            }
            bf16* xo = Xh + (long)id3 * 16;
            *(bf16x8*)xo = lo;
            *(bf16x8*)(xo + 8) = hi;
        }
    }
}

// ---------------------------------------------------------------------------
// mega_kernel — FINAL (r4/r6 proven-best variant, session optimum):
// ONE block = 16 nodes x ALL 3 levels (768 threads, 12 waves; wave-quad lq
// handles level lq). Cross-level max in LDS -> no slabs, no reduce kernel;
// out written once, coalesced f32x4, temporally clustered (r3 lesson:
// scattered-in-time stores get 2.2x write amplification).
// Conv: bf16 Xh gathers (L2-resident 2.56 MB table; 16 B load IS the MFMA
// A-frag), ego-split max_k((g-s)W) = max_k(gW) - sW with sW in registers
// via one shfl_xor(32) (verified 32x32 D-layout row=(g&3)+8*(g>>2)+4*hh),
// all 16 As-index loads hoisted. FETCH 26.5 MB / WRITE 25 MB = compulsory.
// Session-closed findings (r5..r11, all measured):
//  * 2-block residency impossible: 24 waves/CU ⇒ 85-reg cap < 64-reg
//    LSTM weight set ⇒ spill (r5: FETCH 330 MB).
//  * atomic-fmax output sink bypasses L2 regardless of XCD placement
//    (r7/r8: WRITE 149.7 MB, bit-identical under colocation).
//  * scheduling-level changes (dbuf, lgkm barriers, ax prefetch, store
//    placement, gather hoist) all neutral at +/-3 us (r10/r11).
// => per-block wall ~30 us is the co-residency-limited structural floor of
// the 24-step barrier-locked recurrence; not an HBM/MFMA roofline.
// ---------------------------------------------------------------------------
__global__ __launch_bounds__(768, 3) void mega_kernel(
    const bf16* __restrict__ Xh, const int* __restrict__ As,
    const float* __restrict__ conv_w, const float* __restrict__ conv_b,
    const bf16* __restrict__ wts, const float* __restrict__ bias,
    float* __restrict__ out) {
    __shared__ __align__(16) bf16 featL[LL][TT][16][72];   // 55,296 B
    __shared__ __align__(16) bf16 hlds[LL][2][16][72];     // 13,824 B
    __shared__ __align__(16) float yst[LL][2][16][64];     // 24,576 B (ping-pong)

    const int tid = threadIdx.x;
    const int node0 = blockIdx.x * 16;
    const int lq = tid >> 8;            // level 0..2
    const int tl = tid & 255;           // thread-in-quad
    const int lane = tid & 63;
    const int wq = tl >> 6;             // wave-in-quad 0..3
    const int c16 = lane & 15;
    const int q = lane >> 4;
    const int m = lane & 31;            // conv: A row index
    const int hh = lane >> 5;           // conv: k-half
    const int ch0 = hh * 8;
    const int nsub = m >> 4;
    const int kn = m & 15;

    // ================= conv weights -> B fragments =================
    bf16x8 B0, B1;
    {
        const float* w0 = conv_w + ((lq * 64 + m) * 16 + ch0);
        f32x4 a = *(const f32x4*)w0, b = *(const f32x4*)(w0 + 4);
        const float* w1 = conv_w + ((lq * 64 + 32 + m) * 16 + ch0);
        f32x4 c = *(const f32x4*)w1, d = *(const f32x4*)(w1 + 4);
#pragma unroll
        for (int j = 0; j < 4; ++j) {
            B0[j] = (bf16)a[j]; B0[4 + j] = (bf16)b[j];
            B1[j] = (bf16)c[j]; B1[4 + j] = (bf16)d[j];
        }
    }
    const float cb0 = conv_b[lq * 64 + m];
    const float cb1 = conv_b[lq * 64 + 32 + m];

    // ========== 1) hoist ALL 16 As-index loads (one latency) ==========
    int aidx[4][4];
#pragma unroll
    for (int c = 0; c < 4; ++c) {
        const int t0 = (c >> 1) * 4;
        const int gn = node0 + 2 * (2 * wq + (c & 1)) + nsub;
#pragma unroll
        for (int j = 0; j < 4; ++j)
            aidx[c][j] = As[((long)(lq * 8 + t0 + j) * NN + gn) * 16 + kn];
    }

    // ========== 2) ego projection sW in registers (overlaps As latency) ==========
    f32x16 E0, E1;
    {
        bf16x8 ae = *(const bf16x8*)(Xh + ((long)(node0 * 8 + 32 * wq + m)) * 16 + ch0);
#pragma unroll
        for (int k = 0; k < 16; ++k) { E0[k] = 0.0f; E1[k] = 0.0f; }
        E0 = __builtin_amdgcn_mfma_f32_32x32x16_bf16(ae, B0, E0, 0, 0, 0);
        E1 = __builtin_amdgcn_mfma_f32_32x32x16_bf16(ae, B1, E1, 0, 0, 0);
    }

    // ========== 3) gathers (bf16x8 == A-frag), 2-deep chunk pipeline ==========
    bf16x8 gA[4], gB[4];
    auto gload = [&](int c, bf16x8* dst) {
        const int t0 = (c >> 1) * 4;
#pragma unroll
        for (int j = 0; j < 4; ++j)
            dst[j] = *(const bf16x8*)(Xh + ((long)aidx[c][j] * 8 + t0 + j) * 16 + ch0);
    };
    auto proc = [&](int c, const bf16x8* g) {
        const int t0 = (c >> 1) * 4;
        const int pc = 2 * wq + (c & 1);
#pragma unroll
        for (int j = 0; j < 4; ++j) {
            f32x16 D0, D1;
#pragma unroll
            for (int k = 0; k < 16; ++k) { D0[k] = 0.0f; D1[k] = 0.0f; }
            D0 = __builtin_amdgcn_mfma_f32_32x32x16_bf16(g[j], B0, D0, 0, 0, 0);
            D1 = __builtin_amdgcn_mfma_f32_32x32x16_bf16(g[j], B1, D1, 0, 0, 0);

            float v00 = D0[0], v01 = D1[0], v10 = D0[8], v11 = D1[8];
#pragma unroll
            for (int k = 1; k < 8; ++k) {
                v00 = fmaxf(v00, D0[k]);     v01 = fmaxf(v01, D1[k]);
                v10 = fmaxf(v10, D0[8 + k]); v11 = fmaxf(v11, D1[8 + k]);
            }
            v00 = fmaxf(v00, __shfl_xor(v00, 32));
            v01 = fmaxf(v01, __shfl_xor(v01, 32));
            v10 = fmaxf(v10, __shfl_xor(v10, 32));
            v11 = fmaxf(v11, __shfl_xor(v11, 32));

            const float sA = hh ? v10 : v00;   // cols [0,32)
            const float sB = hh ? v11 : v01;   // cols [32,64)

            // sW from registers: bands (compile-time const indices)
            const float a0 = E0[j + 8 * (c & 1)];       // hh_c = 0 band
            const float a1 = E0[j + 8 * (c & 1) + 4];   // hh_c = 1 band
            const float b0 = E1[j + 8 * (c & 1)];
            const float b1 = E1[j + 8 * (c & 1) + 4];
            const float sendA = hh ? a0 : a1;           // what my partner needs
            const float sendB = hh ? b0 : b1;
            const float rcvA = __shfl_xor(sendA, 32);
            const float rcvB = __shfl_xor(sendB, 32);
            const bool loc = (hh == (c >> 1));          // source half = c>>1
            const float swA = loc ? (hh ? a1 : a0) : rcvA;
            const float swB = loc ? (hh ? b1 : b0) : rcvB;

            featL[lq][t0 + j][2 * pc + hh][m]      = (bf16)(sA + cb0 - swA);
            featL[lq][t0 + j][2 * pc + hh][32 + m] = (bf16)(sB + cb1 - swB);
        }
    };
    gload(0, gA); gload(1, gB);
    proc(0, gA);  gload(2, gA);
    proc(1, gB);  gload(3, gB);
    proc(2, gA);
    proc(3, gB);

    // ================= LSTM weights (registers/AGPRs) =================
    const bf16* wb = wts + lq * 32768;
    const int fo = c16 * 32 + q * 8;
    bf16x8 Bx0[4], Bx1[4], Bh0[4], Bh1[4];
    float brg[4];
#pragma unroll
    for (int g = 0; g < 4; ++g) {
        const int nt = 4 * g + wq;
        Bx0[g] = *(const bf16x8*)(wb + (0 * 16 + nt) * 512 + fo);
        Bx1[g] = *(const bf16x8*)(wb + (1 * 16 + nt) * 512 + fo);
        Bh0[g] = *(const bf16x8*)(wb + (2 * 16 + nt) * 512 + fo);
        Bh1[g] = *(const bf16x8*)(wb + (3 * 16 + nt) * 512 + fo);
        brg[g] = bias[lq * 256 + nt * 16 + c16];
    }
    float c_r[4];
#pragma unroll
    for (int r = 0; r < 4; ++r) c_r[r] = 0.0f;

    const int col = wq * 16 + c16;
    const int sn = tl >> 4;             // store mapping (lq==0 quad)
    const int sc = (tl & 15) * 4;

    // ================= 8 recurrent steps =================
#pragma unroll
    for (int t = 0; t < TT; ++t) {
        __syncthreads();  // t=0: featL ready; t>0: h(t-1)/yst(t-1) visible

        if (t > 0 && tid < 256) {   // cross-level max of ys(t-1), coalesced store
            f32x4 y0 = *(const f32x4*)&yst[0][(t - 1) & 1][sn][sc];
            f32x4 y1 = *(const f32x4*)&yst[1][(t - 1) & 1][sn][sc];
            f32x4 y2 = *(const f32x4*)&yst[2][(t - 1) & 1][sn][sc];
            f32x4 dmx;
#pragma unroll
            for (int k = 0; k < 4; ++k) dmx[k] = fmaxf(fmaxf(y0[k], y1[k]), y2[k]);
            *(f32x4*)&out[((long)(node0 + sn) * 8 + (t - 1)) * 64 + sc] = dmx;
        }

        bf16x8 ax0 = *(const bf16x8*)&featL[lq][t][c16][q * 8];
        bf16x8 ax1 = *(const bf16x8*)&featL[lq][t][c16][32 + q * 8];
        bf16x8 ah0, ah1;
        if (t > 0) {
            ah0 = *(const bf16x8*)&hlds[lq][(t + 1) & 1][c16][q * 8];
            ah1 = *(const bf16x8*)&hlds[lq][(t + 1) & 1][c16][32 + q * 8];
        }

        f32x4 acc[4];
#pragma unroll
        for (int g = 0; g < 4; ++g) {
            float b = brg[g];
            acc[g] = (f32x4){b, b, b, b};
            acc[g] = __builtin_amdgcn_mfma_f32_16x16x32_bf16(ax0, Bx0[g], acc[g], 0, 0, 0);
            acc[g] = __builtin_amdgcn_mfma_f32_16x16x32_bf16(ax1, Bx1[g], acc[g], 0, 0, 0);
            if (t > 0) {
                acc[g] = __builtin_amdgcn_mfma_f32_16x16x32_bf16(ah0, Bh0[g], acc[g], 0, 0, 0);
                acc[g] = __builtin_amdgcn_mfma_f32_16x16x32_bf16(ah1, Bh1[g], acc[g], 0, 0, 0);
            }
        }

        // cell: lane holds nodes q*4+r, hidden col wq*16+c16
#pragma unroll
        for (int r = 0; r < 4; ++r) {
            float iv = acc[0][r], fv = acc[1][r], gg = acc[2][r], ov = acc[3][r];
            float c = sigf(fv) * c_r[r] + sigf(iv) * tanhf_(gg);
            c_r[r] = c;
            float h = sigf(ov) * tanhf_(c);
            hlds[lq][t & 1][q * 4 + r][col] = (bf16)h;
            yst[lq][t & 1][q * 4 + r][col] = h;
        }
    }

    // ================= tail: ys(7)=h_final, then c_final =================
    __syncthreads();            // step-7 writes + y(6) store reads complete
#pragma unroll
    for (int r = 0; r < 4; ++r) // stage c in slot 0 (y(6) already consumed)
        yst[lq][0][q * 4 + r][col] = c_r[r];
    if (tid < 256) {
        f32x4 y0 = *(const f32x4*)&yst[0][1][sn][sc];
        f32x4 y1 = *(const f32x4*)&yst[1][1][sn][sc];
        f32x4 y2 = *(const f32x4*)&yst[2][1][sn][sc];
        f32x4 dmx;
#pragma unroll
        for (int k = 0; k < 4; ++k) dmx[k] = fmaxf(fmaxf(y0[k], y1[k]), y2[k]);
        *(f32x4*)&out[((long)(node0 + sn) * 8 + 7) * 64 + sc] = dmx;
        *(f32x4*)&out[H_OFF + (long)(node0 + sn) * 64 + sc] = dmx;
    }
    __syncthreads();
    if (tid < 256) {
        f32x4 c0 = *(const f32x4*)&yst[0][0][sn][sc];
        f32x4 c1 = *(const f32x4*)&yst[1][0][sn][sc];
        f32x4 c2 = *(const f32x4*)&yst[2][0][sn][sc];
        f32x4 dmx;
#pragma unroll
        for (int k = 0; k < 4; ++k) dmx[k] = fmaxf(fmaxf(c0[k], c1[k]), c2[k]);
        *(f32x4*)&out[C_OFF + (long)(node0 + sn) * 64 + sc] = dmx;
    }
}

// ---------------------------------------------------------------------------
// Path B (fallback if ws too small): r6 structure — in-block level loop,
// direct out writes, f32 X. Proven correct.
// ---------------------------------------------------------------------------
__device__ __forceinline__ void level_body(
    int l, int node0, int tid,
    const float* __restrict__ X, const int* __restrict__ As,
    const float* __restrict__ conv_w, const float* __restrict__ conv_b,
    const bf16* __restrict__ wts, const float* __restrict__ bias,
    bf16 (*featL)[16][72], bf16 (*hlds)[16][72],
    float ymax[TT][4], float hfin[4], float cfin[4], bool accum) {
    const int lane = tid & 63;
    const int wv = tid >> 6;
    const int c16 = lane & 15;
    const int q = lane >> 4;
    const int m = lane & 31;
    const int hh = lane >> 5;
    const int ch0 = hh * 8;
    const int nsub = m >> 4;
    const int kn = m & 15;

    bf16x8 B0, B1;
    {
        const float* w0 = conv_w + ((l * 64 + m) * 16 + ch0);
        f32x4 a = *(const f32x4*)w0, b = *(const f32x4*)(w0 + 4);
        const float* w1 = conv_w + ((l * 64 + 32 + m) * 16 + ch0);
        f32x4 c = *(const f32x4*)w1, d = *(const f32x4*)(w1 + 4);
#pragma unroll
        for (int j = 0; j < 4; ++j) {
            B0[j] = (bf16)a[j]; B0[4 + j] = (bf16)b[j];
            B1[j] = (bf16)c[j]; B1[4 + j] = (bf16)d[j];
        }
    }
    const float cb0 = conv_b[l * 64 + m];
    const float cb1 = conv_b[l * 64 + 32 + m];

#pragma unroll 1
    for (int c = 0; c < 4; ++c) {
        const int pc = 2 * wv + (c & 1);
        const int t0 = (c >> 1) * 4;
        const int gn = node0 + 2 * pc + nsub;

        int aidx[4];
#pragma unroll
        for (int j = 0; j < 4; ++j)
            aidx[j] = As[((long)(l * 8 + t0 + j) * NN + gn) * 16 + kn];
        f32x4 sv[4][2], gv[4][2];
#pragma unroll
        for (int j = 0; j < 4; ++j) {
            const float* sp = X + ((gn * 8 + t0 + j) * 16 + ch0);
            sv[j][0] = *(const f32x4*)sp;
            sv[j][1] = *(const f32x4*)(sp + 4);
        }
#pragma unroll
        for (int j = 0; j < 4; ++j) {
            const float* gp = X + (((long)aidx[j] * 8 + t0 + j) * 16 + ch0);
            gv[j][0] = *(const f32x4*)gp;
            gv[j][1] = *(const f32x4*)(gp + 4);
        }

#pragma unroll
        for (int j = 0; j < 4; ++j) {
            bf16x8 af;
#pragma unroll
            for (int k = 0; k < 4; ++k) {
                af[k]     = (bf16)(gv[j][0][k] - sv[j][0][k]);
                af[4 + k] = (bf16)(gv[j][1][k] - sv[j][1][k]);
            }
            f32x16 D0, D1;
#pragma unroll
            for (int k = 0; k < 16; ++k) { D0[k] = 0.0f; D1[k] = 0.0f; }
            D0 = __builtin_amdgcn_mfma_f32_32x32x16_bf16(af, B0, D0, 0, 0, 0);
            D1 = __builtin_amdgcn_mfma_f32_32x32x16_bf16(af, B1, D1, 0, 0, 0);

            float v00 = D0[0], v01 = D1[0], v10 = D0[8], v11 = D1[8];
#pragma unroll
            for (int k = 1; k < 8; ++k) {
                v00 = fmaxf(v00, D0[k]);     v01 = fmaxf(v01, D1[k]);
                v10 = fmaxf(v10, D0[8 + k]); v11 = fmaxf(v11, D1[8 + k]);
            }
            v00 = fmaxf(v00, __shfl_xor(v00, 32));
            v01 = fmaxf(v01, __shfl_xor(v01, 32));
            v10 = fmaxf(v10, __shfl_xor(v10, 32));
            v11 = fmaxf(v11, __shfl_xor(v11, 32));

            const float sA = hh ? v10 : v00;
            const float sB = hh ? v11 : v01;
            featL[t0 + j][2 * pc + hh][m]      = (bf16)(sA + cb0);
            featL[t0 + j][2 * pc + hh][32 + m] = (bf16)(sB + cb1);
        }
    }

    const bf16* wb = wts + l * 32768;
    const int fo = c16 * 32 + q * 8;
    bf16x8 Bx0[4], Bx1[4], Bh0[4], Bh1[4];
    float brg[4];
#pragma unroll
    for (int g = 0; g < 4; ++g) {
        const int nt = 4 * g + wv;
        Bx0[g] = *(const bf16x8*)(wb + (0 * 16 + nt) * 512 + fo);
        Bx1[g] = *(const bf16x8*)(wb + (1 * 16 + nt) * 512 + fo);
        Bh0[g] = *(const bf16x8*)(wb + (2 * 16 + nt) * 512 + fo);
        Bh1[g] = *(const bf16x8*)(wb + (3 * 16 + nt) * 512 + fo);
        brg[g] = bias[l * 256 + nt * 16 + c16];
    }
    float c_r[4];
#pragma unroll
    for (int r = 0; r < 4; ++r) c_r[r] = 0.0f;

#pragma unroll
    for (int t = 0; t < TT; ++t) {
        __syncthreads();

        bf16x8 ax0 = *(const bf16x8*)&featL[t][c16][q * 8];
        bf16x8 ax1 = *(const bf16x8*)&featL[t][c16][32 + q * 8];
        bf16x8 ah0, ah1;
        if (t > 0) {
            ah0 = *(const bf16x8*)&hlds[(t + 1) & 1][c16][q * 8];
            ah1 = *(const bf16x8*)&hlds[(t + 1) & 1][c16][32 + q * 8];
        }

        f32x4 acc[4];
#pragma unroll
        for (int g = 0; g < 4; ++g) {
            float b = brg[g];
            acc[g] = (f32x4){b, b, b, b};
            acc[g] = __builtin_amdgcn_mfma_f32_16x16x32_bf16(ax0, Bx0[g], acc[g], 0, 0, 0);
            acc[g] = __builtin_amdgcn_mfma_f32_16x16x32_bf16(ax1, Bx1[g], acc[g], 0, 0, 0);
            if (t > 0) {
                acc[g] = __builtin_amdgcn_mfma_f32_16x16x32_bf16(ah0, Bh0[g], acc[g], 0, 0, 0);
                acc[g] = __builtin_amdgcn_mfma_f32_16x16x32_bf16(ah1, Bh1[g], acc[g], 0, 0, 0);
            }
        }

#pragma unroll
        for (int r = 0; r < 4; ++r) {
            float iv = acc[0][r], fv = acc[1][r], gg = acc[2][r], ov = acc[3][r];
            float c = sigf(fv) * c_r[r] + sigf(iv) * tanhf_(gg);
            c_r[r] = c;
            float h = sigf(ov) * tanhf_(c);
            hlds[t & 1][q * 4 + r][wv * 16 + c16] = (bf16)h;
            ymax[t][r] = accum ? fmaxf(ymax[t][r], h) : h;
            if (t == TT - 1) {
                hfin[r] = accum ? fmaxf(hfin[r], h) : h;
                cfin[r] = accum ? fmaxf(cfin[r], c) : c;
            }
        }
    }
}

__global__ __launch_bounds__(256, 3) void fused_kernel(
    const float* __restrict__ X, const int* __restrict__ As,
    const float* __restrict__ conv_w, const float* __restrict__ conv_b,
    const bf16* __restrict__ wts, const float* __restrict__ bias,
    float* __restrict__ out) {
    __shared__ __align__(16) bf16 featL[TT][16][72];
    __shared__ __align__(16) bf16 hlds[2][16][72];

    const int tid = threadIdx.x;
    const int node0 = blockIdx.x * 16;

    float ymax[TT][4], hfin[4], cfin[4];
    for (int l = 0; l < LL; ++l) {
        __syncthreads();
        level_body(l, node0, tid, X, As, conv_w, conv_b, wts, bias,
                   featL, hlds, ymax, hfin, cfin, /*accum=*/(l > 0));
    }

    const int lane = tid & 63;
    const int wv = tid >> 6;
    const int c16 = lane & 15;
    const int q = lane >> 4;
    const int col = wv * 16 + c16;
#pragma unroll
    for (int t = 0; t < TT; ++t)
#pragma unroll
        for (int r = 0; r < 4; ++r)
            out[((long)(node0 + q * 4 + r) * 8 + t) * 64 + col] = ymax[t][r];
    float* sh = out + (long)H_OFF;
    float* sc = out + (long)C_OFF;
#pragma unroll
    for (int r = 0; r < 4; ++r) {
        sh[(long)(node0 + q * 4 + r) * 64 + col] = hfin[r];
        sc[(long)(node0 + q * 4 + r) * 64 + col] = cfin[r];
    }
}

extern "C" void kernel_launch(void* const* d_in, const int* in_sizes, int n_in,
                              void* d_out, int out_size, void* d_ws, size_t ws_size,
                              hipStream_t stream) {
    const float* X = (const float*)d_in[0];
    const int* As = (const int*)d_in[1];
    const float* conv_w = (const float*)d_in[4];
    const float* conv_b = (const float*)d_in[5];
    const float* W_ih = (const float*)d_in[6];
    const float* W_hh = (const float*)d_in[7];
    const float* b_ih = (const float*)d_in[8];
    const float* b_hh = (const float*)d_in[9];
    float* out = (float*)d_out;

    char* ws = (char*)d_ws;
    // layout: wts (192 KB) | bias (4 KB slot) | Xh (2.56 MB)
    const size_t xh_bytes = (size_t)NN * TT * 16 * 2;
    const size_t need = 196608 + 4096 + xh_bytes;
    const bool big_ws = ws_size >= need;

    // prep grid: 98304 (wts) + 768 (bias) + 80000 (Xh rows) = 179072 ids
    if (big_ws) {
        bf16* wts = (bf16*)ws;
        float* bias = (float*)(ws + 196608);
        bf16* Xh = (bf16*)(ws + 196608 + 4096);
        hipLaunchKernelGGL(prep_kernel, dim3(700), dim3(256), 0, stream,
                           X, W_ih, W_hh, b_ih, b_hh, wts, bias, Xh);
        hipLaunchKernelGGL(mega_kernel, dim3(NGRP), dim3(768), 0, stream,
                           Xh, As, conv_w, conv_b, wts, bias, out);
    } else {
        bf16* wts = (bf16*)ws;
        float* bias = (float*)(ws + 196608);
        hipLaunchKernelGGL(prep_kernel, dim3(700), dim3(256), 0, stream,
                           X, W_ih, W_hh, b_ih, b_hh, wts, bias, (bf16*)nullptr);
        hipLaunchKernelGGL(fused_kernel, dim3(NGRP), dim3(256), 0, stream,
                           X, As, conv_w, conv_b, wts, bias, out);
    }
}